// Round 3
// baseline (207.359 us; speedup 1.0000x reference)
//
#include <hip/hip_runtime.h>
#include <float.h>
#include <math.h>

#define DIM    1024
#define NROWS  131072
#define TOPK   32
#define TAU    0.2f
#define CHUNK  512
#define NCHUNK (NROWS / CHUNK)   // 256
#define NCAND  (NCHUNK * TOPK)   // 8192

#define LOG_BLOCKS 2048
#define ROWS_PER_WAVE 16         // 2 rows/iter x 8 iters
#define NITER 8

// ---------------------------------------------------------------------------
// Kernel 1: logits[row] = dot(K[row], query)  (raw dot; positive scale applied
// in the final kernel, so top-k order is unaffected). Zeroes full_attn[row].
//
// Persistent grid-stride waves with REGISTER DOUBLE-BUFFERING: the 8 float4
// loads of row-pair r+1 are issued before the waitcnt on row-pair r, so each
// wave keeps ~8KB posted to HBM across the FMA+reduce phase (duty ~100%
// instead of ~40% in the one-shot layout that measured ~2.8 TB/s).
// 32 lanes per row (sub=lane&31), 2 rows per wave-iter (rsel=lane>>5).
// ---------------------------------------------------------------------------
__global__ __launch_bounds__(256) void logits_kernel(const float* __restrict__ Km,
                                                     const float* __restrict__ q,
                                                     float* __restrict__ logits,
                                                     float* __restrict__ full_attn) {
    const int t    = threadIdx.x;
    const int lane = t & 63;
    const int wave = t >> 6;
    const int sub  = lane & 31;   // position within row
    const int rsel = lane >> 5;   // which of the wave's 2 rows this iter

    // q slice for this lane: phase p covers floats p*128 + sub*4 .. +3
    float4 qv[8];
    #pragma unroll
    for (int p = 0; p < 8; ++p)
        qv[p] = *reinterpret_cast<const float4*>(q + p * 128 + sub * 4);

    const int gwave = blockIdx.x * 4 + wave;           // 0 .. 8191
    const int rbase = gwave * ROWS_PER_WAVE;           // 16 contiguous rows
    const float* kptr = Km + (size_t)(rbase + rsel) * DIM + sub * 4;

    float4 buf[2][8];
    #pragma unroll
    for (int p = 0; p < 8; ++p)
        buf[0][p] = *reinterpret_cast<const float4*>(kptr + p * 128);

    #pragma unroll
    for (int r = 0; r < NITER; ++r) {
        const float* knext = kptr + 2 * DIM;
        if (r < NITER - 1) {
            #pragma unroll
            for (int p = 0; p < 8; ++p)
                buf[(r + 1) & 1][p] = *reinterpret_cast<const float4*>(knext + p * 128);
        }
        // 4 parallel accumulators to keep the FMA chain short
        float a0 = 0.f, a1 = 0.f, a2 = 0.f, a3 = 0.f;
        #pragma unroll
        for (int p = 0; p < 8; ++p) {
            float4 kv = buf[r & 1][p];
            float4 qq = qv[p];
            a0 = fmaf(kv.x, qq.x, a0);
            a1 = fmaf(kv.y, qq.y, a1);
            a2 = fmaf(kv.z, qq.z, a2);
            a3 = fmaf(kv.w, qq.w, a3);
        }
        float acc = (a0 + a1) + (a2 + a3);
        // reduce over 32 lanes (xor offsets stay within each 32-lane group)
        #pragma unroll
        for (int off = 1; off < 32; off <<= 1) acc += __shfl_xor(acc, off, 64);
        if (sub == 0) {
            const int row = rbase + 2 * r + rsel;
            logits[row]    = acc;
            full_attn[row] = 0.f;
        }
        kptr = knext;
    }
}

// ---------------------------------------------------------------------------
// Kernel 2: per-block (1 wave) local top-32 of a 512-element chunk.
// 256 blocks -> 8192 (val, idx) candidates; global top-32 is a subset.
// ---------------------------------------------------------------------------
__global__ __launch_bounds__(64) void topk_local_kernel(const float* __restrict__ logits,
                                                        float* __restrict__ cand_val,
                                                        int* __restrict__ cand_idx) {
    const int lane = threadIdx.x;
    const int base = blockIdx.x * CHUNK;

    float v[8]; int gi[8];
    float4 a = *reinterpret_cast<const float4*>(logits + base + lane * 4);
    float4 b = *reinterpret_cast<const float4*>(logits + base + 256 + lane * 4);
    v[0] = a.x; v[1] = a.y; v[2] = a.z; v[3] = a.w;
    v[4] = b.x; v[5] = b.y; v[6] = b.z; v[7] = b.w;
    #pragma unroll
    for (int j = 0; j < 4; ++j) gi[j] = base + lane * 4 + j;
    #pragma unroll
    for (int j = 0; j < 4; ++j) gi[4 + j] = base + 256 + lane * 4 + j;

    for (int r = 0; r < TOPK; ++r) {
        float m = v[0]; int mi = gi[0];
        #pragma unroll
        for (int j = 1; j < 8; ++j)
            if (v[j] > m || (v[j] == m && gi[j] < mi)) { m = v[j]; mi = gi[j]; }
        #pragma unroll
        for (int off = 32; off > 0; off >>= 1) {
            float ov = __shfl_xor(m, off, 64);
            int   oi = __shfl_xor(mi, off, 64);
            if (ov > m || (ov == m && oi < mi)) { m = ov; mi = oi; }
        }
        #pragma unroll
        for (int j = 0; j < 8; ++j)
            if (gi[j] == mi) v[j] = -FLT_MAX;   // only the owner matches
        if (lane == 0) {
            cand_val[blockIdx.x * TOPK + r] = m;
            cand_idx[blockIdx.x * TOPK + r] = mi;
        }
    }
}

// ---------------------------------------------------------------------------
// Kernel 3 (1 block, 256 threads): computes scale = 1/(max(||q||,1e-12)*TAU),
// global top-32 of 8192 candidates (incremental per-thread running max),
// softmax of the scaled values, scatter into full_attn, out = attn @ V[idxs].
// ---------------------------------------------------------------------------
__global__ __launch_bounds__(256) void final_kernel(const float* __restrict__ cand_val,
                                                    const int* __restrict__ cand_idx,
                                                    const float* __restrict__ q,
                                                    const float* __restrict__ Vm,
                                                    float* __restrict__ out,
                                                    float* __restrict__ full_attn) {
    const int t = threadIdx.x;
    const int lane = t & 63, wave = t >> 6;
    __shared__ float wred_v[4];
    __shared__ int   wred_i[4];
    __shared__ float tval[TOPK];
    __shared__ int   tidx[TOPK];
    __shared__ float attn_s[TOPK];
    __shared__ float red4[4];
    __shared__ float scale_s;

    // ---- scale = 1 / (max(||q||,1e-12) * TAU) ----
    float ss = 0.f;
    for (int i = t; i < DIM; i += 256) { float vq = q[i]; ss = fmaf(vq, vq, ss); }
    #pragma unroll
    for (int off = 32; off > 0; off >>= 1) ss += __shfl_xor(ss, off, 64);
    if (lane == 0) red4[wave] = ss;
    __syncthreads();
    if (t == 0) {
        float s = red4[0] + red4[1] + red4[2] + red4[3];
        scale_s = 1.0f / (fmaxf(sqrtf(s), 1e-12f) * TAU);
    }

    // ---- load candidates (coalesced), per-thread running max ----
    float v[32]; int gi[32];
    #pragma unroll
    for (int k = 0; k < 32; ++k) {
        int c = t + 256 * k;
        v[k]  = cand_val[c];
        gi[k] = cand_idx[c];
    }
    float m = v[0]; int mi = gi[0];
    #pragma unroll
    for (int k = 1; k < 32; ++k)
        if (v[k] > m || (v[k] == m && gi[k] < mi)) { m = v[k]; mi = gi[k]; }

    __syncthreads();   // scale_s published

    // ---- 32 rounds of global argmax; only the winner's thread rescans ----
    for (int r = 0; r < TOPK; ++r) {
        float wm = m; int wmi = mi;
        #pragma unroll
        for (int off = 32; off > 0; off >>= 1) {
            float ov = __shfl_xor(wm, off, 64);
            int   oi = __shfl_xor(wmi, off, 64);
            if (ov > wm || (ov == wm && oi < wmi)) { wm = ov; wmi = oi; }
        }
        if (lane == 0) { wred_v[wave] = wm; wred_i[wave] = wmi; }
        __syncthreads();
        float gm = wred_v[0]; int gmi = wred_i[0];
        #pragma unroll
        for (int w = 1; w < 4; ++w) {
            float ov = wred_v[w]; int oi = wred_i[w];
            if (ov > gm || (ov == gm && oi < gmi)) { gm = ov; gmi = oi; }
        }
        if (t == 0) { tval[r] = gm; tidx[r] = gmi; }
        if (mi == gmi) {              // candidate indices are unique: 1 owner
            #pragma unroll
            for (int k = 0; k < 32; ++k)
                if (gi[k] == gmi) v[k] = -FLT_MAX;
            m = v[0]; mi = gi[0];
            #pragma unroll
            for (int k = 1; k < 32; ++k)
                if (v[k] > m || (v[k] == m && gi[k] < mi)) { m = v[k]; mi = gi[k]; }
        }
        __syncthreads();   // protects wred_* reuse, publishes tval/tidx
    }

    // ---- softmax over scaled top values (tval[0] is the max; scale>0) ----
    const float scale = scale_s;
    float sum = 0.f;
    #pragma unroll
    for (int j = 0; j < TOPK; ++j) sum += expf((tval[j] - tval[0]) * scale);
    if (t < TOPK) attn_s[t] = expf((tval[t] - tval[0]) * scale) / sum;
    __syncthreads();

    if (t < TOPK) full_attn[tidx[t]] = attn_s[t];

    // ---- out[d] = sum_j attn[j] * V[idx[j]][d] (coalesced over d) ----
    for (int d = t; d < DIM; d += 256) {
        float acc = 0.f;
        #pragma unroll
        for (int j = 0; j < TOPK; ++j)
            acc = fmaf(attn_s[j], Vm[(size_t)tidx[j] * DIM + d], acc);
        out[d] = acc;
    }
}

// ---------------------------------------------------------------------------
extern "C" void kernel_launch(void* const* d_in, const int* in_sizes, int n_in,
                              void* d_out, int out_size, void* d_ws, size_t ws_size,
                              hipStream_t stream) {
    const float* q  = (const float*)d_in[0];
    const float* Km = (const float*)d_in[1];
    const float* Vm = (const float*)d_in[2];
    // d_in[3] = topk scalar (32) — fixed by problem setup.

    float* out       = (float*)d_out;       // [0 .. 1024)
    float* full_attn = out + DIM;           // [1024 .. 1024+131072)

    float* logits   = (float*)d_ws;                 // NROWS floats
    float* cand_val = logits + NROWS;               // NCAND floats
    int*   cand_idx = (int*)(cand_val + NCAND);     // NCAND ints

    logits_kernel<<<LOG_BLOCKS, 256, 0, stream>>>(Km, q, logits, full_attn);
    topk_local_kernel<<<NCHUNK, 64, 0, stream>>>(logits, cand_val, cand_idx);
    final_kernel<<<1, 256, 0, stream>>>(cand_val, cand_idx, q, Vm, out, full_attn);
}

// Round 5
// 187.758 us; speedup vs baseline: 1.1044x; 1.1044x over previous
//
#include <hip/hip_runtime.h>
#include <float.h>
#include <math.h>

#define DIM    1024
#define NROWS  131072
#define TOPK   32
#define TAU    0.2f
#define CHUNK  512
#define NCHUNK (NROWS / CHUNK)   // 256
#define NCAND  (NCHUNK * TOPK)   // 8192

#define LOG_BLOCKS 2048
#define ROWS_PER_WAVE 16         // 2 rows/iter x 8 iters
#define NITER 8

// Native clang vector type (HIP_vector_type<float,4> is a struct and is
// rejected by __builtin_nontemporal_load).
typedef float floatx4 __attribute__((ext_vector_type(4)));

// Non-temporal 16B load: emits global_load_dwordx4 ... nt, streaming past
// the L2/L3 allocation path (zero-reuse 512MB K stream).
__device__ __forceinline__ floatx4 ld_nt(const float* p) {
    return __builtin_nontemporal_load(reinterpret_cast<const floatx4*>(p));
}

// ---------------------------------------------------------------------------
// Kernel 1: logits[row] = dot(K[row], query)  (raw dot; positive scale applied
// in the final kernel, so top-k order is unaffected). Zeroes full_attn[row].
// Persistent waves, register double-buffer, NON-TEMPORAL K loads.
// ---------------------------------------------------------------------------
__global__ __launch_bounds__(256) void logits_kernel(const float* __restrict__ Km,
                                                     const float* __restrict__ q,
                                                     float* __restrict__ logits,
                                                     float* __restrict__ full_attn) {
    const int t    = threadIdx.x;
    const int lane = t & 63;
    const int wave = t >> 6;
    const int sub  = lane & 31;   // position within row
    const int rsel = lane >> 5;   // which of the wave's 2 rows this iter

    // q slice for this lane: phase p covers floats p*128 + sub*4 .. +3
    floatx4 qv[8];
    #pragma unroll
    for (int p = 0; p < 8; ++p)
        qv[p] = *reinterpret_cast<const floatx4*>(q + p * 128 + sub * 4);

    const int gwave = blockIdx.x * 4 + wave;           // 0 .. 8191
    const int rbase = gwave * ROWS_PER_WAVE;           // 16 contiguous rows
    const float* kptr = Km + (size_t)(rbase + rsel) * DIM + sub * 4;

    floatx4 buf[2][8];
    #pragma unroll
    for (int p = 0; p < 8; ++p)
        buf[0][p] = ld_nt(kptr + p * 128);

    #pragma unroll
    for (int r = 0; r < NITER; ++r) {
        const float* knext = kptr + 2 * DIM;
        if (r < NITER - 1) {
            #pragma unroll
            for (int p = 0; p < 8; ++p)
                buf[(r + 1) & 1][p] = ld_nt(knext + p * 128);
        }
        // 4 parallel accumulators to keep the FMA chain short
        float a0 = 0.f, a1 = 0.f, a2 = 0.f, a3 = 0.f;
        #pragma unroll
        for (int p = 0; p < 8; ++p) {
            floatx4 kv = buf[r & 1][p];
            floatx4 qq = qv[p];
            a0 = fmaf(kv.x, qq.x, a0);
            a1 = fmaf(kv.y, qq.y, a1);
            a2 = fmaf(kv.z, qq.z, a2);
            a3 = fmaf(kv.w, qq.w, a3);
        }
        float acc = (a0 + a1) + (a2 + a3);
        // reduce over 32 lanes (xor offsets stay within each 32-lane group)
        #pragma unroll
        for (int off = 1; off < 32; off <<= 1) acc += __shfl_xor(acc, off, 64);
        if (sub == 0) {
            const int row = rbase + 2 * r + rsel;
            logits[row]    = acc;
            full_attn[row] = 0.f;
        }
        kptr = knext;
    }
}

// ---------------------------------------------------------------------------
// Kernel 2: per-block (1 wave) local top-32 of a 512-element chunk.
// 256 blocks -> 8192 (val, idx) candidates; global top-32 is a subset.
// ---------------------------------------------------------------------------
__global__ __launch_bounds__(64) void topk_local_kernel(const float* __restrict__ logits,
                                                        float* __restrict__ cand_val,
                                                        int* __restrict__ cand_idx) {
    const int lane = threadIdx.x;
    const int base = blockIdx.x * CHUNK;

    float v[8]; int gi[8];
    floatx4 a = *reinterpret_cast<const floatx4*>(logits + base + lane * 4);
    floatx4 b = *reinterpret_cast<const floatx4*>(logits + base + 256 + lane * 4);
    v[0] = a.x; v[1] = a.y; v[2] = a.z; v[3] = a.w;
    v[4] = b.x; v[5] = b.y; v[6] = b.z; v[7] = b.w;
    #pragma unroll
    for (int j = 0; j < 4; ++j) gi[j] = base + lane * 4 + j;
    #pragma unroll
    for (int j = 0; j < 4; ++j) gi[4 + j] = base + 256 + lane * 4 + j;

    for (int r = 0; r < TOPK; ++r) {
        float m = v[0]; int mi = gi[0];
        #pragma unroll
        for (int j = 1; j < 8; ++j)
            if (v[j] > m || (v[j] == m && gi[j] < mi)) { m = v[j]; mi = gi[j]; }
        #pragma unroll
        for (int off = 32; off > 0; off >>= 1) {
            float ov = __shfl_xor(m, off, 64);
            int   oi = __shfl_xor(mi, off, 64);
            if (ov > m || (ov == m && oi < mi)) { m = ov; mi = oi; }
        }
        #pragma unroll
        for (int j = 0; j < 8; ++j)
            if (gi[j] == mi) v[j] = -FLT_MAX;   // only the owner matches
        if (lane == 0) {
            cand_val[blockIdx.x * TOPK + r] = m;
            cand_idx[blockIdx.x * TOPK + r] = mi;
        }
    }
}

// ---------------------------------------------------------------------------
// Kernel 3 (1 block, 256 threads): computes scale = 1/(max(||q||,1e-12)*TAU),
// global top-32 of 8192 candidates (incremental per-thread running max),
// softmax of the scaled values, scatter into full_attn, out = attn @ V[idxs].
// ---------------------------------------------------------------------------
__global__ __launch_bounds__(256) void final_kernel(const float* __restrict__ cand_val,
                                                    const int* __restrict__ cand_idx,
                                                    const float* __restrict__ q,
                                                    const float* __restrict__ Vm,
                                                    float* __restrict__ out,
                                                    float* __restrict__ full_attn) {
    const int t = threadIdx.x;
    const int lane = t & 63, wave = t >> 6;
    __shared__ float wred_v[4];
    __shared__ int   wred_i[4];
    __shared__ float tval[TOPK];
    __shared__ int   tidx[TOPK];
    __shared__ float attn_s[TOPK];
    __shared__ float red4[4];
    __shared__ float scale_s;

    // ---- scale = 1 / (max(||q||,1e-12) * TAU) ----
    float ss = 0.f;
    for (int i = t; i < DIM; i += 256) { float vq = q[i]; ss = fmaf(vq, vq, ss); }
    #pragma unroll
    for (int off = 32; off > 0; off >>= 1) ss += __shfl_xor(ss, off, 64);
    if (lane == 0) red4[wave] = ss;
    __syncthreads();
    if (t == 0) {
        float s = red4[0] + red4[1] + red4[2] + red4[3];
        scale_s = 1.0f / (fmaxf(sqrtf(s), 1e-12f) * TAU);
    }

    // ---- load candidates (coalesced), per-thread running max ----
    float v[32]; int gi[32];
    #pragma unroll
    for (int k = 0; k < 32; ++k) {
        int c = t + 256 * k;
        v[k]  = cand_val[c];
        gi[k] = cand_idx[c];
    }
    float m = v[0]; int mi = gi[0];
    #pragma unroll
    for (int k = 1; k < 32; ++k)
        if (v[k] > m || (v[k] == m && gi[k] < mi)) { m = v[k]; mi = gi[k]; }

    __syncthreads();   // scale_s published

    // ---- 32 rounds of global argmax; only the winner's thread rescans ----
    for (int r = 0; r < TOPK; ++r) {
        float wm = m; int wmi = mi;
        #pragma unroll
        for (int off = 32; off > 0; off >>= 1) {
            float ov = __shfl_xor(wm, off, 64);
            int   oi = __shfl_xor(wmi, off, 64);
            if (ov > wm || (ov == wm && oi < wmi)) { wm = ov; wmi = oi; }
        }
        if (lane == 0) { wred_v[wave] = wm; wred_i[wave] = wmi; }
        __syncthreads();
        float gm = wred_v[0]; int gmi = wred_i[0];
        #pragma unroll
        for (int w = 1; w < 4; ++w) {
            float ov = wred_v[w]; int oi = wred_i[w];
            if (ov > gm || (ov == gm && oi < gmi)) { gm = ov; gmi = oi; }
        }
        if (t == 0) { tval[r] = gm; tidx[r] = gmi; }
        if (mi == gmi) {              // candidate indices are unique: 1 owner
            #pragma unroll
            for (int k = 0; k < 32; ++k)
                if (gi[k] == gmi) v[k] = -FLT_MAX;
            m = v[0]; mi = gi[0];
            #pragma unroll
            for (int k = 1; k < 32; ++k)
                if (v[k] > m || (v[k] == m && gi[k] < mi)) { m = v[k]; mi = gi[k]; }
        }
        __syncthreads();   // protects wred_* reuse, publishes tval/tidx
    }

    // ---- softmax over scaled top values (tval[0] is the max; scale>0) ----
    const float scale = scale_s;
    float sum = 0.f;
    #pragma unroll
    for (int j = 0; j < TOPK; ++j) sum += expf((tval[j] - tval[0]) * scale);
    if (t < TOPK) attn_s[t] = expf((tval[t] - tval[0]) * scale) / sum;
    __syncthreads();

    if (t < TOPK) full_attn[tidx[t]] = attn_s[t];

    // ---- out[d] = sum_j attn[j] * V[idx[j]][d] (coalesced over d) ----
    for (int d = t; d < DIM; d += 256) {
        float acc = 0.f;
        #pragma unroll
        for (int j = 0; j < TOPK; ++j)
            acc = fmaf(attn_s[j], Vm[(size_t)tidx[j] * DIM + d], acc);
        out[d] = acc;
    }
}

// ---------------------------------------------------------------------------
extern "C" void kernel_launch(void* const* d_in, const int* in_sizes, int n_in,
                              void* d_out, int out_size, void* d_ws, size_t ws_size,
                              hipStream_t stream) {
    const float* q  = (const float*)d_in[0];
    const float* Km = (const float*)d_in[1];
    const float* Vm = (const float*)d_in[2];
    // d_in[3] = topk scalar (32) — fixed by problem setup.

    float* out       = (float*)d_out;       // [0 .. 1024)
    float* full_attn = out + DIM;           // [1024 .. 1024+131072)

    float* logits   = (float*)d_ws;                 // NROWS floats
    float* cand_val = logits + NROWS;               // NCAND floats
    int*   cand_idx = (int*)(cand_val + NCAND);     // NCAND ints

    logits_kernel<<<LOG_BLOCKS, 256, 0, stream>>>(Km, q, logits, full_attn);
    topk_local_kernel<<<NCHUNK, 64, 0, stream>>>(logits, cand_val, cand_idx);
    final_kernel<<<1, 256, 0, stream>>>(cand_val, cand_idx, q, Vm, out, full_attn);
}